// Round 6
// baseline (442.582 us; speedup 1.0000x reference)
//
#include <hip/hip_runtime.h>

// B=32, N=36, D=2048, C=4, H=512.  K = 2H = 1024 stacked (coord|feat).
// Out[b,i,d] = max_j sum_k Wcat[k,d] * (crfr[b,j,k] * clfl[b,i,k]) + mm[b,i,d]

typedef __attribute__((ext_vector_type(8))) short short8;
typedef __attribute__((ext_vector_type(4))) short short4v;
typedef __attribute__((ext_vector_type(4))) float f32x4;

__device__ __forceinline__ float bf2f(unsigned short h) {
  return __uint_as_float(((unsigned int)h) << 16);
}
__device__ __forceinline__ unsigned short f2bf(float f) {
  unsigned int u = __float_as_uint(f);
  u += 0x7FFFu + ((u >> 16) & 1u);
  return (unsigned short)(u >> 16);
}

// ---------------------------------------------------------------------------
// K_prep: bid<2304: coords proj (cl->Lw[:,0:512], cr->Rw[:,0:512]) + mm->bf16.
//         bid>=2304: weights -> MFMA fragment order (WS for K4, WS2 for K3).
__global__ __launch_bounds__(256) void k_prep(
    const float* __restrict__ coords, const float* __restrict__ Wcl,
    const float* __restrict__ Wcr, const float* __restrict__ mm,
    const float* __restrict__ Wcout, const float* __restrict__ Wfout,
    const float* __restrict__ Wfl, const float* __restrict__ Wfr,
    unsigned short* __restrict__ Lw, unsigned short* __restrict__ Rw,
    unsigned short* __restrict__ mmb, unsigned short* __restrict__ WS,
    unsigned short* __restrict__ WS2) {
  const int bid = blockIdx.x;
  if (bid < 2304) {
    int idx = bid * 256 + threadIdx.x;  // 0 .. 1152*512-1
    int row = idx >> 9, h = idx & 511;
    const float* c = coords + row * 4;
    float a0 = c[0], a1 = c[1], a2 = c[2], a3 = c[3];
    float vl = a0 * Wcl[h] + a1 * Wcl[512 + h] + a2 * Wcl[1024 + h] + a3 * Wcl[1536 + h];
    float vr = a0 * Wcr[h] + a1 * Wcr[512 + h] + a2 * Wcr[1024 + h] + a3 * Wcr[1536 + h];
    Lw[(size_t)row * 1024 + h] = f2bf(vl);
    Rw[(size_t)row * 1024 + h] = f2bf(vr);
    float4 m4 = *(const float4*)(mm + (size_t)row * 2048 + h * 4);
    short4v o;
    o[0] = (short)f2bf(m4.x); o[1] = (short)f2bf(m4.y);
    o[2] = (short)f2bf(m4.z); o[3] = (short)f2bf(m4.w);
    *(short4v*)(mmb + (size_t)row * 2048 + h * 4) = o;
  } else {
    int gi = (bid - 2304) * 256 + threadIdx.x;  // 0..524287
    if (gi < 262144) {
      // WS granule gi = ((g2*32+kc)*4+q)*16+n ; elem e: d=g2*16+n, k=kc*32+q*8+e
      int n = gi & 15, qv = (gi >> 4) & 3, kc = (gi >> 6) & 31, g2 = gi >> 11;
      int d = g2 * 16 + n;
      int kbase = kc * 32 + qv * 8;
      const float* src = (kbase < 512) ? (Wcout + (size_t)kbase * 2048 + d)
                                       : (Wfout + (size_t)(kbase - 512) * 2048 + d);
      short8 o;
#pragma unroll
      for (int e = 0; e < 8; ++e) o[e] = (short)f2bf(src[(size_t)e * 2048]);
      *(short8*)(WS + (size_t)gi * 8) = o;
    } else {
      // WS2 granule gj = ((cg*64+kc)*4+q)*16+n ; elem e: col=cg*16+n, dd=kc*32+q*8+e
      int gj = gi - 262144;
      int n = gj & 15, qv = (gj >> 4) & 3, kc = (gj >> 6) & 63, cg = gj >> 12;
      int col = cg * 16 + n;
      int dbase = kc * 32 + qv * 8;
      const float* src = (col < 512) ? (Wfl + (size_t)dbase * 512 + col)
                                     : (Wfr + (size_t)dbase * 512 + (col - 512));
      short8 o;
#pragma unroll
      for (int e = 0; e < 8; ++e) o[e] = (short)f2bf(src[(size_t)e * 512]);
      *(short8*)(WS2 + (size_t)gj * 8) = o;
    }
  }
}

// ---------------------------------------------------------------------------
// K3: feature projection O[row,col] = sum_dd mmb[row,dd]*Wlr[dd,col]
//  col<512 -> fl -> Lw[row][512+col] ; else fr -> Rw[row][col]
__global__ __launch_bounds__(256) void k_proj_feat(
    const unsigned short* __restrict__ mmb, const unsigned short* __restrict__ WS2,
    unsigned short* __restrict__ Lw, unsigned short* __restrict__ Rw) {
  const int tid = threadIdx.x;
  const int lane = tid & 63, w = tid >> 6;
  const int n = lane & 15, q = lane >> 4;
  const int m0 = blockIdx.y * 16;
  const int cg = blockIdx.x * 4 + w;  // 0..63
  const int c0 = cg * 16;

  f32x4 acc = {0.f, 0.f, 0.f, 0.f};
#pragma unroll 4
  for (int kc = 0; kc < 64; ++kc) {
    short8 a = *(const short8*)(mmb + (size_t)(m0 + n) * 2048 + kc * 32 + q * 8);
    short8 b = *(const short8*)(WS2 + (size_t)(cg * 64 + kc) * 512 + lane * 8);
    acc = __builtin_amdgcn_mfma_f32_16x16x32_bf16(a, b, acc, 0, 0, 0);
  }
#pragma unroll
  for (int e = 0; e < 4; ++e) {
    int row = m0 + q * 4 + e;
    int col = c0 + n;
    unsigned short v = f2bf(acc[e]);
    if (col < 512) Lw[(size_t)row * 1024 + 512 + col] = v;
    else           Rw[(size_t)row * 1024 + col] = v;
  }
}

// ---------------------------------------------------------------------------
// K4: fused pairwise GEMM + max-over-j + residual, products computed in-block
// (no Pf tensor, no fetch-bound stream). Quad-packed 9-tile B (zero padding):
//   t<8 : g = g0+(t>>1), j = (t&1)*16+n ; t=8 : g = g0+(n>>2), j = 32+(n&3)
// Block: 512 thr (8 waves), one quad-group (4 i's) x 256-d tile.
// grid 2304 = qg*8+dt (bx&7=dt -> W-slice per XCD L2-resident).
// Per chunk (32 k): 576 product slots (9 granules x 512) staged by VALU into
// dbuf LDS (~9 elems/thread, ~30 VALU cyc vs 342 MFMA cyc/wave); A from WS
// (reg dbuf). acc 9 tiles x 2 r = 72 AGPR.
__global__ __launch_bounds__(512, 2) void k_pairwise(
    const unsigned short* __restrict__ Lw, const unsigned short* __restrict__ Rw,
    const unsigned short* __restrict__ WS, const float* __restrict__ mm,
    float* __restrict__ out) {
  __shared__ __align__(16) unsigned short lB[2][9 * 512];  // 2 x 9 KB

  const int tid = threadIdx.x;
  const int lane = tid & 63, w = tid >> 6;  // w 0..7
  const int n = lane & 15, q = lane >> 4;
  const int bx = blockIdx.x;
  const int dt = bx & 7, qg = bx >> 3;  // dt 0..7, qg 0..287
  const int g0 = qg * 4;
  const int b = qg / 9;

  // staging slot A (all 512 threads): slot = tid, granule t = tid>>6
  const int tA = tid >> 6, lsA = tid & 63, nA = lsA & 15, qA = lsA >> 4;
  const int gA = g0 + (tA >> 1);
  const int jA = (tA & 1) * 16 + nA;
  const unsigned short* clA = Lw + (size_t)gA * 1024 + qA * 8;
  const unsigned short* crA = Rw + (size_t)(b * 36 + jA) * 1024 + qA * 8;
  const int offA = tA * 512 + lsA * 8;
  // staging slot B (tid<64): slot = 512+tid, granule t=8 (shared remainder)
  const bool hasB = (tid < 64);
  const int nB = tid & 15, qB = (tid >> 4) & 3;
  const int gB = g0 + (nB >> 2);
  const int jB = 32 + (nB & 3);
  const unsigned short* clB = Lw + (size_t)gB * 1024 + qB * 8;
  const unsigned short* crB = Rw + (size_t)(b * 36 + jB) * 1024 + qB * 8;
  const int offB = 8 * 512 + tid * 8;

  short8 sclA, scrA, sclB, scrB;
#define SLOAD(kc_)                                                   \
  do {                                                               \
    sclA = *(const short8*)(clA + (kc_) * 32);                       \
    scrA = *(const short8*)(crA + (kc_) * 32);                       \
    if (hasB) {                                                      \
      sclB = *(const short8*)(clB + (kc_) * 32);                     \
      scrB = *(const short8*)(crB + (kc_) * 32);                     \
    }                                                                \
  } while (0)

#define SFIN(buf_)                                                   \
  do {                                                               \
    short8 p;                                                        \
    _Pragma("unroll") for (int e = 0; e < 8; ++e)                    \
        p[e] = (short)f2bf(bf2f((unsigned short)sclA[e]) *           \
                           bf2f((unsigned short)scrA[e]));           \
    *(short8*)(&lB[buf_][offA]) = p;                                 \
    if (hasB) {                                                      \
      short8 pb;                                                     \
      _Pragma("unroll") for (int e = 0; e < 8; ++e)                  \
          pb[e] = (short)f2bf(bf2f((unsigned short)sclB[e]) *        \
                              bf2f((unsigned short)scrB[e]));        \
      *(short8*)(&lB[buf_][offB]) = pb;                              \
    }                                                                \
  } while (0)

  f32x4 acc[9][2];
#pragma unroll
  for (int t = 0; t < 9; ++t)
#pragma unroll
    for (int r = 0; r < 2; ++r) acc[t][r] = (f32x4){0.f, 0.f, 0.f, 0.f};

  // A granule (r, kc): WS + ((dt*16 + w*2 + r)*32 + kc)*512 + lane*8
  const unsigned short* Abase = WS + ((size_t)(dt * 16 + w * 2) * 32) * 512 + lane * 8;
  short8 aR[2], aN[2];

  // prologue: products for kc=0 into buf 0, A(kc=0) into regs
  SLOAD(0);
  SFIN(0);
  aR[0] = *(const short8*)(Abase);
  aR[1] = *(const short8*)(Abase + 32 * 512);
  __syncthreads();

#pragma unroll 2
  for (int kc = 0; kc < 32; ++kc) {
    const int buf = kc & 1;
    if (kc < 31) {
      SLOAD(kc + 1);
      aN[0] = *(const short8*)(Abase + (size_t)(kc + 1) * 512);
      aN[1] = *(const short8*)(Abase + (size_t)(32 + kc + 1) * 512);
    }
    short8 bb[9];
#pragma unroll
    for (int t = 0; t < 9; ++t)
      bb[t] = *(const short8*)(&lB[buf][t * 512 + lane * 8]);
#pragma unroll
    for (int t = 0; t < 9; ++t) {
      acc[t][0] = __builtin_amdgcn_mfma_f32_16x16x32_bf16(aR[0], bb[t], acc[t][0], 0, 0, 0);
      acc[t][1] = __builtin_amdgcn_mfma_f32_16x16x32_bf16(aR[1], bb[t], acc[t][1], 0, 0, 0);
    }
    if (kc < 31) SFIN(buf ^ 1);
    __syncthreads();  // writes to buf^1 visible; reads of buf done
    aR[0] = aN[0];
    aR[1] = aN[1];
  }
#undef SLOAD
#undef SFIN

  // epilogue: per (ii,r,e): max over full tiles 2ii,2ii+1 (j=n, 16+n) and the
  // shared tile's lanes with n>>2==ii (j=32+(n&3)); xor-reduce over 16 n-lanes.
#pragma unroll
  for (int r = 0; r < 2; ++r) {
#pragma unroll
    for (int e = 0; e < 4; ++e) {
      float vs = acc[8][r][e];
#pragma unroll
      for (int ii = 0; ii < 4; ++ii) {
        float v = fmaxf(acc[ii * 2][r][e], acc[ii * 2 + 1][r][e]);
        v = fmaxf(v, ((n >> 2) == ii) ? vs : -1e30f);
#pragma unroll
        for (int s = 1; s < 16; s <<= 1) v = fmaxf(v, __shfl_xor(v, s, 64));
        if (n == 0) {
          int d = dt * 256 + w * 32 + r * 16 + q * 4 + e;
          size_t o = (size_t)(g0 + ii) * 2048 + d;
          out[o] = v + mm[o];
        }
      }
    }
  }
}

// ---------------------------------------------------------------------------
extern "C" void kernel_launch(void* const* d_in, const int* in_sizes, int n_in,
                              void* d_out, int out_size, void* d_ws, size_t ws_size,
                              hipStream_t stream) {
  const float* mm     = (const float*)d_in[0];
  const float* coords = (const float*)d_in[1];
  const float* Wcl    = (const float*)d_in[2];
  const float* Wcr    = (const float*)d_in[3];
  const float* Wcout  = (const float*)d_in[4];
  const float* Wfl    = (const float*)d_in[5];
  const float* Wfr    = (const float*)d_in[6];
  const float* Wfout  = (const float*)d_in[7];
  float* out = (float*)d_out;

  // workspace (bf16 shorts), ~18 MB total
  unsigned short* Lw  = (unsigned short*)d_ws;   // [1152][1024]  cl | fl
  unsigned short* Rw  = Lw + 1152 * 1024;        // [1152][1024]  cr | fr
  unsigned short* WS  = Rw + 1152 * 1024;        // 262144 granules x 8 (Wcat^T frag)
  unsigned short* WS2 = WS + (size_t)262144 * 8; // 262144 granules x 8 ((Wfl|Wfr)^T frag)
  unsigned short* mmb = WS2 + (size_t)262144 * 8;// [1152][2048]  mm in bf16

  k_prep<<<2304 + 2048, 256, 0, stream>>>(coords, Wcl, Wcr, mm, Wcout, Wfout,
                                          Wfl, Wfr, Lw, Rw, mmb, WS, WS2);
  k_proj_feat<<<dim3(16, 72), 256, 0, stream>>>(mmb, WS2, Lw, Rw);
  k_pairwise<<<2304, 512, 0, stream>>>(Lw, Rw, WS, mm, out);
}

// Round 7
// 386.465 us; speedup vs baseline: 1.1452x; 1.1452x over previous
//
#include <hip/hip_runtime.h>

// B=32, N=36, D=2048, C=4, H=512.  K = 2H = 1024 stacked (coord|feat).
// Out[b,i,d] = max_j sum_k Wcat[k,d] * (crfr[b,j,k] * clfl[b,i,k]) + mm[b,i,d]

typedef __attribute__((ext_vector_type(8))) short short8;
typedef __attribute__((ext_vector_type(4))) short short4v;
typedef __attribute__((ext_vector_type(4))) float f32x4;

__device__ __forceinline__ float bf2f(unsigned short h) {
  return __uint_as_float(((unsigned int)h) << 16);
}
__device__ __forceinline__ unsigned short f2bf(float f) {
  unsigned int u = __float_as_uint(f);
  u += 0x7FFFu + ((u >> 16) & 1u);
  return (unsigned short)(u >> 16);
}

// ---------------------------------------------------------------------------
// K_prep: bid<2304: coords proj (cl->Lw[:,0:512], cr->Rw[:,0:512]) + mm->bf16.
//         bid>=2304: weights -> MFMA fragment order (WS for K4, WS2 for K3).
__global__ __launch_bounds__(256) void k_prep(
    const float* __restrict__ coords, const float* __restrict__ Wcl,
    const float* __restrict__ Wcr, const float* __restrict__ mm,
    const float* __restrict__ Wcout, const float* __restrict__ Wfout,
    const float* __restrict__ Wfl, const float* __restrict__ Wfr,
    unsigned short* __restrict__ Lw, unsigned short* __restrict__ Rw,
    unsigned short* __restrict__ mmb, unsigned short* __restrict__ WS,
    unsigned short* __restrict__ WS2) {
  const int bid = blockIdx.x;
  if (bid < 2304) {
    int idx = bid * 256 + threadIdx.x;  // 0 .. 1152*512-1
    int row = idx >> 9, h = idx & 511;
    const float* c = coords + row * 4;
    float a0 = c[0], a1 = c[1], a2 = c[2], a3 = c[3];
    float vl = a0 * Wcl[h] + a1 * Wcl[512 + h] + a2 * Wcl[1024 + h] + a3 * Wcl[1536 + h];
    float vr = a0 * Wcr[h] + a1 * Wcr[512 + h] + a2 * Wcr[1024 + h] + a3 * Wcr[1536 + h];
    Lw[(size_t)row * 1024 + h] = f2bf(vl);
    Rw[(size_t)row * 1024 + h] = f2bf(vr);
    float4 m4 = *(const float4*)(mm + (size_t)row * 2048 + h * 4);
    short4v o;
    o[0] = (short)f2bf(m4.x); o[1] = (short)f2bf(m4.y);
    o[2] = (short)f2bf(m4.z); o[3] = (short)f2bf(m4.w);
    *(short4v*)(mmb + (size_t)row * 2048 + h * 4) = o;
  } else {
    int gi = (bid - 2304) * 256 + threadIdx.x;  // 0..524287
    if (gi < 262144) {
      // WS granule gi = ((g2*32+kc)*4+q)*16+n ; elem e: d=g2*16+n, k=kc*32+q*8+e
      int n = gi & 15, qv = (gi >> 4) & 3, kc = (gi >> 6) & 31, g2 = gi >> 11;
      int d = g2 * 16 + n;
      int kbase = kc * 32 + qv * 8;
      const float* src = (kbase < 512) ? (Wcout + (size_t)kbase * 2048 + d)
                                       : (Wfout + (size_t)(kbase - 512) * 2048 + d);
      short8 o;
#pragma unroll
      for (int e = 0; e < 8; ++e) o[e] = (short)f2bf(src[(size_t)e * 2048]);
      *(short8*)(WS + (size_t)gi * 8) = o;
    } else {
      // WS2 granule gj = ((cg*64+kc)*4+q)*16+n ; elem e: col=cg*16+n, dd=kc*32+q*8+e
      int gj = gi - 262144;
      int n = gj & 15, qv = (gj >> 4) & 3, kc = (gj >> 6) & 63, cg = gj >> 12;
      int col = cg * 16 + n;
      int dbase = kc * 32 + qv * 8;
      const float* src = (col < 512) ? (Wfl + (size_t)dbase * 512 + col)
                                     : (Wfr + (size_t)dbase * 512 + (col - 512));
      short8 o;
#pragma unroll
      for (int e = 0; e < 8; ++e) o[e] = (short)f2bf(src[(size_t)e * 512]);
      *(short8*)(WS2 + (size_t)gj * 8) = o;
    }
  }
}

// ---------------------------------------------------------------------------
// K3: feature projection O[row,col] = sum_dd mmb[row,dd]*Wlr[dd,col]
//  col<512 -> fl -> Lw[row][512+col] ; else fr -> Rw[row][col]
__global__ __launch_bounds__(256) void k_proj_feat(
    const unsigned short* __restrict__ mmb, const unsigned short* __restrict__ WS2,
    unsigned short* __restrict__ Lw, unsigned short* __restrict__ Rw) {
  const int tid = threadIdx.x;
  const int lane = tid & 63, w = tid >> 6;
  const int n = lane & 15, q = lane >> 4;
  const int m0 = blockIdx.y * 16;
  const int cg = blockIdx.x * 4 + w;  // 0..63
  const int c0 = cg * 16;

  f32x4 acc = {0.f, 0.f, 0.f, 0.f};
#pragma unroll 4
  for (int kc = 0; kc < 64; ++kc) {
    short8 a = *(const short8*)(mmb + (size_t)(m0 + n) * 2048 + kc * 32 + q * 8);
    short8 b = *(const short8*)(WS2 + (size_t)(cg * 64 + kc) * 512 + lane * 8);
    acc = __builtin_amdgcn_mfma_f32_16x16x32_bf16(a, b, acc, 0, 0, 0);
  }
#pragma unroll
  for (int e = 0; e < 4; ++e) {
    int row = m0 + q * 4 + e;
    int col = c0 + n;
    unsigned short v = f2bf(acc[e]);
    if (col < 512) Lw[(size_t)row * 1024 + 512 + col] = v;
    else           Rw[(size_t)row * 1024 + col] = v;
  }
}

// ---------------------------------------------------------------------------
// K4: fused pairwise GEMM + max-over-j + residual. All cl/cr rows LDS-resident
// (loaded once per block), products staged from LDS -> no global latency in
// the K-loop; A (W) is the only global stream (coalesced, reg-dbuf).
// Quad-packed 9-tile B (zero padding):
//   t<8 : g = g0+(t>>1), j = (t&1)*16+n ; t=8 : g = g0+(n>>2), j = 32+(n&3)
// Block: 512 thr (8 waves), one quad-group (4 i's) x 256-d tile.
// grid 2304 = qg*8+dt (bx&7=dt -> W-slice per XCD L2-resident).
// crL rows padded +8 shorts (stride 1032): 16-row ds_read_b128 is 2-way
// aliased = free (m136). LDS total ~99 KB -> 1 block/CU, 2 waves/SIMD.
__global__ __launch_bounds__(512, 2) void k_pairwise(
    const unsigned short* __restrict__ Lw, const unsigned short* __restrict__ Rw,
    const unsigned short* __restrict__ WS, const float* __restrict__ mm,
    float* __restrict__ out) {
  __shared__ __align__(16) unsigned short crL[36 * 1032];  // 74304 B
  __shared__ __align__(16) unsigned short clL[4 * 1024];   //  8192 B
  __shared__ __align__(16) unsigned short lB[2][9 * 512];  // 18432 B

  const int tid = threadIdx.x;
  const int lane = tid & 63, w = tid >> 6;  // w 0..7
  const int n = lane & 15, q = lane >> 4;
  const int bx = blockIdx.x;
  const int dt = bx & 7, qg = bx >> 3;  // dt 0..7, qg 0..287
  const int g0 = qg * 4;
  const int b = qg / 9;

  // ---- prologue: fill crL (36 rows) + clL (4 rows) from global, coalesced
#pragma unroll
  for (int it = 0; it < 9; ++it) {
    int c = tid + it * 512;            // 0..4607
    int j = c >> 7, k8 = c & 127;
    *(short8*)(crL + j * 1032 + k8 * 8) =
        *(const short8*)(Rw + (size_t)(b * 36 + j) * 1024 + k8 * 8);
  }
  {
    int g = tid >> 7, k8 = tid & 127;
    *(short8*)(clL + g * 1024 + k8 * 8) =
        *(const short8*)(Lw + (size_t)(g0 + g) * 1024 + k8 * 8);
  }

  // staging slot A (all 512 threads): granule t = w, lane (n,q)
  const int clOffA = (w >> 1) * 1024 + q * 8;
  const int crOffA = ((w & 1) * 16 + n) * 1032 + q * 8;
  const int offA = w * 512 + lane * 8;
  // staging slot B (tid<64): granule t=8 (shared remainder tile)
  const bool hasB = (tid < 64);
  const int nB = tid & 15, qB = (tid >> 4) & 3;
  const int clOffB = (nB >> 2) * 1024 + qB * 8;
  const int crOffB = (32 + (nB & 3)) * 1032 + qB * 8;
  const int offB = 8 * 512 + tid * 8;

  short8 sclA, scrA, sclB, scrB;
#define SLOAD(kc_)                                                   \
  do {                                                               \
    sclA = *(const short8*)(clL + clOffA + (kc_) * 32);              \
    scrA = *(const short8*)(crL + crOffA + (kc_) * 32);              \
    if (hasB) {                                                      \
      sclB = *(const short8*)(clL + clOffB + (kc_) * 32);            \
      scrB = *(const short8*)(crL + crOffB + (kc_) * 32);            \
    }                                                                \
  } while (0)

#define SFIN(buf_)                                                   \
  do {                                                               \
    short8 p;                                                        \
    _Pragma("unroll") for (int e = 0; e < 8; ++e)                    \
        p[e] = (short)f2bf(bf2f((unsigned short)sclA[e]) *           \
                           bf2f((unsigned short)scrA[e]));           \
    *(short8*)(&lB[buf_][offA]) = p;                                 \
    if (hasB) {                                                      \
      short8 pb;                                                     \
      _Pragma("unroll") for (int e = 0; e < 8; ++e)                  \
          pb[e] = (short)f2bf(bf2f((unsigned short)sclB[e]) *        \
                              bf2f((unsigned short)scrB[e]));        \
      *(short8*)(&lB[buf_][offB]) = pb;                              \
    }                                                                \
  } while (0)

  f32x4 acc[9][2];
#pragma unroll
  for (int t = 0; t < 9; ++t)
#pragma unroll
    for (int r = 0; r < 2; ++r) acc[t][r] = (f32x4){0.f, 0.f, 0.f, 0.f};

  // A granule (r, kc): WS + ((dt*16 + w*2 + r)*32 + kc)*512 + lane*8
  const unsigned short* Abase = WS + ((size_t)(dt * 16 + w * 2) * 32) * 512 + lane * 8;
  short8 aR[2], aN[2];

  aR[0] = *(const short8*)(Abase);
  aR[1] = *(const short8*)(Abase + 32 * 512);
  __syncthreads();  // crL/clL visible
  SLOAD(0);
  SFIN(0);
  __syncthreads();  // lB[0] ready

#pragma unroll 2
  for (int kc = 0; kc < 32; ++kc) {
    const int buf = kc & 1;
    if (kc < 31) {
      SLOAD(kc + 1);
      aN[0] = *(const short8*)(Abase + (size_t)(kc + 1) * 512);
      aN[1] = *(const short8*)(Abase + (size_t)(32 + kc + 1) * 512);
    }
    short8 bb[9];
#pragma unroll
    for (int t = 0; t < 9; ++t)
      bb[t] = *(const short8*)(&lB[buf][t * 512 + lane * 8]);
#pragma unroll
    for (int t = 0; t < 9; ++t) {
      acc[t][0] = __builtin_amdgcn_mfma_f32_16x16x32_bf16(aR[0], bb[t], acc[t][0], 0, 0, 0);
      acc[t][1] = __builtin_amdgcn_mfma_f32_16x16x32_bf16(aR[1], bb[t], acc[t][1], 0, 0, 0);
    }
    if (kc < 31) SFIN(buf ^ 1);
    __syncthreads();  // writes to buf^1 visible; reads of buf done
    aR[0] = aN[0];
    aR[1] = aN[1];
  }
#undef SLOAD
#undef SFIN

  // epilogue: per (ii,r,e): max over full tiles 2ii,2ii+1 (j=n, 16+n) and the
  // shared tile's lanes with n>>2==ii (j=32+(n&3)); xor-reduce over 16 n-lanes.
#pragma unroll
  for (int r = 0; r < 2; ++r) {
#pragma unroll
    for (int e = 0; e < 4; ++e) {
      float vs = acc[8][r][e];
#pragma unroll
      for (int ii = 0; ii < 4; ++ii) {
        float v = fmaxf(acc[ii * 2][r][e], acc[ii * 2 + 1][r][e]);
        v = fmaxf(v, ((n >> 2) == ii) ? vs : -1e30f);
#pragma unroll
        for (int s = 1; s < 16; s <<= 1) v = fmaxf(v, __shfl_xor(v, s, 64));
        if (n == 0) {
          int d = dt * 256 + w * 32 + r * 16 + q * 4 + e;
          size_t o = (size_t)(g0 + ii) * 2048 + d;
          out[o] = v + mm[o];
        }
      }
    }
  }
}

// ---------------------------------------------------------------------------
extern "C" void kernel_launch(void* const* d_in, const int* in_sizes, int n_in,
                              void* d_out, int out_size, void* d_ws, size_t ws_size,
                              hipStream_t stream) {
  const float* mm     = (const float*)d_in[0];
  const float* coords = (const float*)d_in[1];
  const float* Wcl    = (const float*)d_in[2];
  const float* Wcr    = (const float*)d_in[3];
  const float* Wcout  = (const float*)d_in[4];
  const float* Wfl    = (const float*)d_in[5];
  const float* Wfr    = (const float*)d_in[6];
  const float* Wfout  = (const float*)d_in[7];
  float* out = (float*)d_out;

  // workspace (bf16 shorts), ~18 MB total
  unsigned short* Lw  = (unsigned short*)d_ws;   // [1152][1024]  cl | fl
  unsigned short* Rw  = Lw + 1152 * 1024;        // [1152][1024]  cr | fr
  unsigned short* WS  = Rw + 1152 * 1024;        // 262144 granules x 8 (Wcat^T frag)
  unsigned short* WS2 = WS + (size_t)262144 * 8; // 262144 granules x 8 ((Wfl|Wfr)^T frag)
  unsigned short* mmb = WS2 + (size_t)262144 * 8;// [1152][2048]  mm in bf16

  k_prep<<<2304 + 2048, 256, 0, stream>>>(coords, Wcl, Wcr, mm, Wcout, Wfout,
                                          Wfl, Wfr, Lw, Rw, mmb, WS, WS2);
  k_proj_feat<<<dim3(16, 72), 256, 0, stream>>>(mmb, WS2, Lw, Rw);
  k_pairwise<<<2304, 512, 0, stream>>>(Lw, Rw, WS, mm, out);
}

// Round 8
// 378.201 us; speedup vs baseline: 1.1702x; 1.0219x over previous
//
#include <hip/hip_runtime.h>

// B=32, N=36, D=2048, C=4, H=512.  K = 2H = 1024 stacked (coord|feat).
// Out[b,i,d] = max_j sum_k Wcat[k,d] * (crfr[b,j,k] * clfl[b,i,k]) + mm[b,i,d]

typedef __attribute__((ext_vector_type(8))) short short8;
typedef __attribute__((ext_vector_type(4))) short short4v;
typedef __attribute__((ext_vector_type(4))) float f32x4;

__device__ __forceinline__ float bf2f(unsigned short h) {
  return __uint_as_float(((unsigned int)h) << 16);
}
__device__ __forceinline__ unsigned short f2bf(float f) {
  unsigned int u = __float_as_uint(f);
  u += 0x7FFFu + ((u >> 16) & 1u);
  return (unsigned short)(u >> 16);
}
// async global->LDS, 16B per lane; lds dest is wave-uniform base + lane*16
__device__ __forceinline__ void gl2lds16(const void* g, void* l) {
  __builtin_amdgcn_global_load_lds(
      (const __attribute__((address_space(1))) unsigned int*)g,
      (__attribute__((address_space(3))) unsigned int*)l, 16, 0, 0);
}

// ---------------------------------------------------------------------------
// K_prep: bid<2304: coords proj (cl->Lw[:,0:512], cr->Rw[:,0:512]) + mm->bf16.
//         bid>=2304: weights -> MFMA fragment order (WS for K4, WS2 for K3).
__global__ __launch_bounds__(256) void k_prep(
    const float* __restrict__ coords, const float* __restrict__ Wcl,
    const float* __restrict__ Wcr, const float* __restrict__ mm,
    const float* __restrict__ Wcout, const float* __restrict__ Wfout,
    const float* __restrict__ Wfl, const float* __restrict__ Wfr,
    unsigned short* __restrict__ Lw, unsigned short* __restrict__ Rw,
    unsigned short* __restrict__ mmb, unsigned short* __restrict__ WS,
    unsigned short* __restrict__ WS2) {
  const int bid = blockIdx.x;
  if (bid < 2304) {
    int idx = bid * 256 + threadIdx.x;  // 0 .. 1152*512-1
    int row = idx >> 9, h = idx & 511;
    const float* c = coords + row * 4;
    float a0 = c[0], a1 = c[1], a2 = c[2], a3 = c[3];
    float vl = a0 * Wcl[h] + a1 * Wcl[512 + h] + a2 * Wcl[1024 + h] + a3 * Wcl[1536 + h];
    float vr = a0 * Wcr[h] + a1 * Wcr[512 + h] + a2 * Wcr[1024 + h] + a3 * Wcr[1536 + h];
    Lw[(size_t)row * 1024 + h] = f2bf(vl);
    Rw[(size_t)row * 1024 + h] = f2bf(vr);
    float4 m4 = *(const float4*)(mm + (size_t)row * 2048 + h * 4);
    short4v o;
    o[0] = (short)f2bf(m4.x); o[1] = (short)f2bf(m4.y);
    o[2] = (short)f2bf(m4.z); o[3] = (short)f2bf(m4.w);
    *(short4v*)(mmb + (size_t)row * 2048 + h * 4) = o;
  } else {
    int gi = (bid - 2304) * 256 + threadIdx.x;  // 0..524287
    if (gi < 262144) {
      // WS granule gi = ((g2*32+kc)*4+q)*16+n ; elem e: d=g2*16+n, k=kc*32+q*8+e
      int n = gi & 15, qv = (gi >> 4) & 3, kc = (gi >> 6) & 31, g2 = gi >> 11;
      int d = g2 * 16 + n;
      int kbase = kc * 32 + qv * 8;
      const float* src = (kbase < 512) ? (Wcout + (size_t)kbase * 2048 + d)
                                       : (Wfout + (size_t)(kbase - 512) * 2048 + d);
      short8 o;
#pragma unroll
      for (int e = 0; e < 8; ++e) o[e] = (short)f2bf(src[(size_t)e * 2048]);
      *(short8*)(WS + (size_t)gi * 8) = o;
    } else {
      // WS2 granule gj = ((cg*64+kc)*4+q)*16+n ; elem e: col=cg*16+n, dd=kc*32+q*8+e
      int gj = gi - 262144;
      int n = gj & 15, qv = (gj >> 4) & 3, kc = (gj >> 6) & 63, cg = gj >> 12;
      int col = cg * 16 + n;
      int dbase = kc * 32 + qv * 8;
      const float* src = (col < 512) ? (Wfl + (size_t)dbase * 512 + col)
                                     : (Wfr + (size_t)dbase * 512 + (col - 512));
      short8 o;
#pragma unroll
      for (int e = 0; e < 8; ++e) o[e] = (short)f2bf(src[(size_t)e * 512]);
      *(short8*)(WS2 + (size_t)gj * 8) = o;
    }
  }
}

// ---------------------------------------------------------------------------
// K3: feature projection O[row,col] = sum_dd mmb[row,dd]*Wlr[dd,col]
//  col<512 -> fl -> Lw[row][512+col] ; else fr -> Rw[row][col]
__global__ __launch_bounds__(256) void k_proj_feat(
    const unsigned short* __restrict__ mmb, const unsigned short* __restrict__ WS2,
    unsigned short* __restrict__ Lw, unsigned short* __restrict__ Rw) {
  const int tid = threadIdx.x;
  const int lane = tid & 63, w = tid >> 6;
  const int n = lane & 15, q = lane >> 4;
  const int m0 = blockIdx.y * 16;
  const int cg = blockIdx.x * 4 + w;  // 0..63
  const int c0 = cg * 16;

  f32x4 acc = {0.f, 0.f, 0.f, 0.f};
#pragma unroll 4
  for (int kc = 0; kc < 64; ++kc) {
    short8 a = *(const short8*)(mmb + (size_t)(m0 + n) * 2048 + kc * 32 + q * 8);
    short8 b = *(const short8*)(WS2 + (size_t)(cg * 64 + kc) * 512 + lane * 8);
    acc = __builtin_amdgcn_mfma_f32_16x16x32_bf16(a, b, acc, 0, 0, 0);
  }
#pragma unroll
  for (int e = 0; e < 4; ++e) {
    int row = m0 + q * 4 + e;
    int col = c0 + n;
    unsigned short v = f2bf(acc[e]);
    if (col < 512) Lw[(size_t)row * 1024 + 512 + col] = v;
    else           Rw[(size_t)row * 1024 + col] = v;
  }
}

// ---------------------------------------------------------------------------
// K_prod: materialize pair products in MFMA B-fragment order, quad-packed.
// Granule id = (qg*32 + kc)*9 + t ; lane (q,n), elem e: k = kc*32 + q*8 + e.
//   t<8 : group g = qg*4 + (t>>1), col j = (t&1)*16 + n      (full tiles)
//   t=8 : group g = qg*4 + (n>>2), col j = 32 + (n&3)        (shared remainder)
// P = clfl[g,k] * crfr[b,j,k], bf16. Writes perfectly coalesced (idx*16B).
__global__ __launch_bounds__(256) void k_prod(
    const unsigned short* __restrict__ Lw, const unsigned short* __restrict__ Rw,
    unsigned short* __restrict__ Pf) {
  int idx = blockIdx.x * 256 + threadIdx.x;  // 0 .. 5,308,415
  int lane = idx & 63;
  int gran = idx >> 6;          // 0 .. 82943
  int qg = gran / 288;          // 288 granules per quad-group (32 kc * 9 t)
  int rem = gran - qg * 288;
  int kc = rem / 9;
  int t = rem - kc * 9;
  int n = lane & 15, q = lane >> 4;
  int k0 = kc * 32 + q * 8;
  int b = qg / 9;
  int g, j;
  if (t < 8) { g = qg * 4 + (t >> 1); j = (t & 1) * 16 + n; }
  else       { g = qg * 4 + (n >> 2); j = 32 + (n & 3); }
  short8 cl8 = *(const short8*)(Lw + (size_t)g * 1024 + k0);
  short8 cr8 = *(const short8*)(Rw + (size_t)(b * 36 + j) * 1024 + k0);
  short8 p;
#pragma unroll
  for (int e = 0; e < 8; ++e)
    p[e] = (short)f2bf(bf2f((unsigned short)cl8[e]) * bf2f((unsigned short)cr8[e]));
  *(short8*)(Pf + (size_t)idx * 8) = p;
}

// ---------------------------------------------------------------------------
// K4: streaming GEMM + max-over-j + residual.
// Block: 256 thr (4 waves), one quad-group x 256-d tile; wave = 9 tiles x
// r=4 d-granules (acc 144 regs, launch_bounds(256,2) -> 2 blocks/CU, 8 waves).
// grid 2304, bx = dt*288+qg -> bx%8 = qg%8: all 8 dt-blocks of a qg land on
// ONE XCD -> Pf slice fetched once, served from L2 (r5 refetched 4x from HBM).
// Per chunk (32 k): 9 KB DMA staged (global_load_lds dbuf) + 36 KB LDS reads
// + 36 MFMA/wave -> LDS ~57 us total < MFMA floor 73 us: MFMA-bound.
__global__ __launch_bounds__(256, 2) void k_pairwise(
    const unsigned short* __restrict__ Pf, const unsigned short* __restrict__ WS,
    const float* __restrict__ mm, float* __restrict__ out) {
  __shared__ __align__(16) unsigned short lB[2][9 * 512];  // 2 x 9 KB

  const int tid = threadIdx.x;
  const int lane = tid & 63, w = tid >> 6;  // w 0..3
  const int n = lane & 15, q = lane >> 4;
  const int bx = blockIdx.x;
  const int dt = bx / 288, qg = bx % 288;
  const int g0 = qg * 4;

  f32x4 acc[9][4];
#pragma unroll
  for (int t = 0; t < 9; ++t)
#pragma unroll
    for (int r = 0; r < 4; ++r) acc[t][r] = (f32x4){0.f, 0.f, 0.f, 0.f};

  // A granule (dgrp=w*4+r, kc): WS + ((dt*16 + dgrp)*32 + kc)*512 + lane*8
  const unsigned short* Abase = WS + (size_t)(dt * 16 + w * 4) * 32 * 512 + lane * 8;
  // B granule (kc, t): Pf + ((qg*32 + kc)*9 + t)*512 + lane*8
  const unsigned short* Bbase = Pf + (size_t)qg * 32 * 9 * 512;

  short8 aR[4], aN[4];
  // prologue: stage kc=0 (wave w: tiles w, 4+w; wave 0 also tile 8), load A(0)
  gl2lds16(Bbase + (size_t)w * 512 + lane * 8, &lB[0][w * 512]);
  gl2lds16(Bbase + (size_t)(4 + w) * 512 + lane * 8, &lB[0][(4 + w) * 512]);
  if (w == 0) gl2lds16(Bbase + (size_t)8 * 512 + lane * 8, &lB[0][8 * 512]);
#pragma unroll
  for (int r = 0; r < 4; ++r)
    aR[r] = *(const short8*)(Abase + (size_t)r * 32 * 512);
  __syncthreads();  // vmcnt(0) drain before barrier -> lB[0] ready

  for (int kc = 0; kc < 32; ++kc) {
    const int buf = kc & 1;
    if (kc < 31) {
      const unsigned short* bn = Bbase + (size_t)((kc + 1) * 9) * 512 + lane * 8;
      gl2lds16(bn + (size_t)w * 512, &lB[buf ^ 1][w * 512]);
      gl2lds16(bn + (size_t)(4 + w) * 512, &lB[buf ^ 1][(4 + w) * 512]);
      if (w == 0) gl2lds16(bn + (size_t)8 * 512, &lB[buf ^ 1][8 * 512]);
#pragma unroll
      for (int r = 0; r < 4; ++r)
        aN[r] = *(const short8*)(Abase + (size_t)(r * 32 + kc + 1) * 512);
    }
    short8 bb[9];
#pragma unroll
    for (int t = 0; t < 9; ++t)
      bb[t] = *(const short8*)(&lB[buf][t * 512 + lane * 8]);
#pragma unroll
    for (int t = 0; t < 9; ++t)
#pragma unroll
      for (int r = 0; r < 4; ++r)
        acc[t][r] = __builtin_amdgcn_mfma_f32_16x16x32_bf16(aR[r], bb[t], acc[t][r], 0, 0, 0);
    __syncthreads();  // all waves done reading buf; staged buf^1 complete
#pragma unroll
    for (int r = 0; r < 4; ++r) aR[r] = aN[r];
  }

  // epilogue: per (r,e,ii): max over full tiles 2ii,2ii+1 (j=n, 16+n) and the
  // shared tile's lanes with n>>2==ii (j=32+(n&3)); xor-reduce over 16 n-lanes.
#pragma unroll
  for (int r = 0; r < 4; ++r) {
#pragma unroll
    for (int e = 0; e < 4; ++e) {
      float vs = acc[8][r][e];
#pragma unroll
      for (int ii = 0; ii < 4; ++ii) {
        float v = fmaxf(acc[ii * 2][r][e], acc[ii * 2 + 1][r][e]);
        v = fmaxf(v, ((n >> 2) == ii) ? vs : -1e30f);
#pragma unroll
        for (int s = 1; s < 16; s <<= 1) v = fmaxf(v, __shfl_xor(v, s, 64));
        if (n == 0) {
          int d = dt * 256 + (w * 4 + r) * 16 + q * 4 + e;
          size_t o = (size_t)(g0 + ii) * 2048 + d;
          out[o] = v + mm[o];
        }
      }
    }
  }
}

// ---------------------------------------------------------------------------
extern "C" void kernel_launch(void* const* d_in, const int* in_sizes, int n_in,
                              void* d_out, int out_size, void* d_ws, size_t ws_size,
                              hipStream_t stream) {
  const float* mm     = (const float*)d_in[0];
  const float* coords = (const float*)d_in[1];
  const float* Wcl    = (const float*)d_in[2];
  const float* Wcr    = (const float*)d_in[3];
  const float* Wcout  = (const float*)d_in[4];
  const float* Wfl    = (const float*)d_in[5];
  const float* Wfr    = (const float*)d_in[6];
  const float* Wfout  = (const float*)d_in[7];
  float* out = (float*)d_out;

  // workspace (bf16 shorts), ~103 MB total
  unsigned short* Lw  = (unsigned short*)d_ws;   // [1152][1024]  cl | fl
  unsigned short* Rw  = Lw + 1152 * 1024;        // [1152][1024]  cr | fr
  unsigned short* WS  = Rw + 1152 * 1024;        // 262144 granules x 8 (Wcat^T frag)
  unsigned short* WS2 = WS + (size_t)262144 * 8; // 262144 granules x 8 ((Wfl|Wfr)^T frag)
  unsigned short* mmb = WS2 + (size_t)262144 * 8;// [1152][2048]  mm in bf16
  unsigned short* Pf  = mmb + (size_t)1152 * 2048; // 82944 granules x 512 (products, 85MB)

  k_prep<<<2304 + 2048, 256, 0, stream>>>(coords, Wcl, Wcr, mm, Wcout, Wfout,
                                          Wfl, Wfr, Lw, Rw, mmb, WS, WS2);
  k_proj_feat<<<dim3(16, 72), 256, 0, stream>>>(mmb, WS2, Lw, Rw);
  k_prod<<<20736, 256, 0, stream>>>(Lw, Rw, Pf);
  k_pairwise<<<2304, 256, 0, stream>>>(Pf, WS, mm, out);
}

// Round 9
// 354.212 us; speedup vs baseline: 1.2495x; 1.0677x over previous
//
#include <hip/hip_runtime.h>

// B=32, N=36, D=2048, C=4, H=512.  K = 2H = 1024 stacked (coord|feat).
// Out[b,i,d] = max_j sum_k Wcat[k,d] * (crfr[b,j,k] * clfl[b,i,k]) + mm[b,i,d]

typedef __attribute__((ext_vector_type(8))) short short8;
typedef __attribute__((ext_vector_type(4))) short short4v;
typedef __attribute__((ext_vector_type(4))) float f32x4;

__device__ __forceinline__ float bf2f(unsigned short h) {
  return __uint_as_float(((unsigned int)h) << 16);
}
__device__ __forceinline__ unsigned short f2bf(float f) {
  unsigned int u = __float_as_uint(f);
  u += 0x7FFFu + ((u >> 16) & 1u);
  return (unsigned short)(u >> 16);
}
// async global->LDS, 16B per lane; lds dest is wave-uniform base + lane*16
__device__ __forceinline__ void gl2lds16(const void* g, void* l) {
  __builtin_amdgcn_global_load_lds(
      (const __attribute__((address_space(1))) unsigned int*)g,
      (__attribute__((address_space(3))) unsigned int*)l, 16, 0, 0);
}

// ---------------------------------------------------------------------------
// K_prep: bid<2304: coords proj (cl->Lw[:,0:512], cr->Rw[:,0:512]) + mm->bf16.
//         bid>=2304: weights -> MFMA fragment order (WS for K4, WS2 for K3).
__global__ __launch_bounds__(256) void k_prep(
    const float* __restrict__ coords, const float* __restrict__ Wcl,
    const float* __restrict__ Wcr, const float* __restrict__ mm,
    const float* __restrict__ Wcout, const float* __restrict__ Wfout,
    const float* __restrict__ Wfl, const float* __restrict__ Wfr,
    unsigned short* __restrict__ Lw, unsigned short* __restrict__ Rw,
    unsigned short* __restrict__ mmb, unsigned short* __restrict__ WS,
    unsigned short* __restrict__ WS2) {
  const int bid = blockIdx.x;
  if (bid < 2304) {
    int idx = bid * 256 + threadIdx.x;  // 0 .. 1152*512-1
    int row = idx >> 9, h = idx & 511;
    const float* c = coords + row * 4;
    float a0 = c[0], a1 = c[1], a2 = c[2], a3 = c[3];
    float vl = a0 * Wcl[h] + a1 * Wcl[512 + h] + a2 * Wcl[1024 + h] + a3 * Wcl[1536 + h];
    float vr = a0 * Wcr[h] + a1 * Wcr[512 + h] + a2 * Wcr[1024 + h] + a3 * Wcr[1536 + h];
    Lw[(size_t)row * 1024 + h] = f2bf(vl);
    Rw[(size_t)row * 1024 + h] = f2bf(vr);
    float4 m4 = *(const float4*)(mm + (size_t)row * 2048 + h * 4);
    short4v o;
    o[0] = (short)f2bf(m4.x); o[1] = (short)f2bf(m4.y);
    o[2] = (short)f2bf(m4.z); o[3] = (short)f2bf(m4.w);
    *(short4v*)(mmb + (size_t)row * 2048 + h * 4) = o;
  } else {
    int gi = (bid - 2304) * 256 + threadIdx.x;  // 0..524287
    if (gi < 262144) {
      // WS granule gi = ((g2*32+kc)*4+q)*16+n ; elem e: d=g2*16+n, k=kc*32+q*8+e
      int n = gi & 15, qv = (gi >> 4) & 3, kc = (gi >> 6) & 31, g2 = gi >> 11;
      int d = g2 * 16 + n;
      int kbase = kc * 32 + qv * 8;
      const float* src = (kbase < 512) ? (Wcout + (size_t)kbase * 2048 + d)
                                       : (Wfout + (size_t)(kbase - 512) * 2048 + d);
      short8 o;
#pragma unroll
      for (int e = 0; e < 8; ++e) o[e] = (short)f2bf(src[(size_t)e * 2048]);
      *(short8*)(WS + (size_t)gi * 8) = o;
    } else {
      // WS2 granule gj = ((cg*64+kc)*4+q)*16+n ; elem e: col=cg*16+n, dd=kc*32+q*8+e
      int gj = gi - 262144;
      int n = gj & 15, qv = (gj >> 4) & 3, kc = (gj >> 6) & 63, cg = gj >> 12;
      int col = cg * 16 + n;
      int dbase = kc * 32 + qv * 8;
      const float* src = (col < 512) ? (Wfl + (size_t)dbase * 512 + col)
                                     : (Wfr + (size_t)dbase * 512 + (col - 512));
      short8 o;
#pragma unroll
      for (int e = 0; e < 8; ++e) o[e] = (short)f2bf(src[(size_t)e * 512]);
      *(short8*)(WS2 + (size_t)gj * 8) = o;
    }
  }
}

// ---------------------------------------------------------------------------
// K3: feature projection O[row,col] = sum_dd mmb[row,dd]*Wlr[dd,col]
//  col<512 -> fl -> Lw[row][512+col] ; else fr -> Rw[row][col]
__global__ __launch_bounds__(256) void k_proj_feat(
    const unsigned short* __restrict__ mmb, const unsigned short* __restrict__ WS2,
    unsigned short* __restrict__ Lw, unsigned short* __restrict__ Rw) {
  const int tid = threadIdx.x;
  const int lane = tid & 63, w = tid >> 6;
  const int n = lane & 15, q = lane >> 4;
  const int m0 = blockIdx.y * 16;
  const int cg = blockIdx.x * 4 + w;  // 0..63
  const int c0 = cg * 16;

  f32x4 acc = {0.f, 0.f, 0.f, 0.f};
#pragma unroll 4
  for (int kc = 0; kc < 64; ++kc) {
    short8 a = *(const short8*)(mmb + (size_t)(m0 + n) * 2048 + kc * 32 + q * 8);
    short8 b = *(const short8*)(WS2 + (size_t)(cg * 64 + kc) * 512 + lane * 8);
    acc = __builtin_amdgcn_mfma_f32_16x16x32_bf16(a, b, acc, 0, 0, 0);
  }
#pragma unroll
  for (int e = 0; e < 4; ++e) {
    int row = m0 + q * 4 + e;
    int col = c0 + n;
    unsigned short v = f2bf(acc[e]);
    if (col < 512) Lw[(size_t)row * 1024 + 512 + col] = v;
    else           Rw[(size_t)row * 1024 + col] = v;
  }
}

// ---------------------------------------------------------------------------
// K_prod: materialize pair products in MFMA B-fragment order, quad-packed.
// Granule id = (qg*32 + kc)*9 + t ; lane (q,n), elem e: k = kc*32 + q*8 + e.
//   t<8 : group g = qg*4 + (t>>1), col j = (t&1)*16 + n      (full tiles)
//   t=8 : group g = qg*4 + (n>>2), col j = 32 + (n&3)        (shared remainder)
// P = clfl[g,k] * crfr[b,j,k], bf16. Writes perfectly coalesced (idx*16B).
__global__ __launch_bounds__(256) void k_prod(
    const unsigned short* __restrict__ Lw, const unsigned short* __restrict__ Rw,
    unsigned short* __restrict__ Pf) {
  int idx = blockIdx.x * 256 + threadIdx.x;  // 0 .. 5,308,415
  int lane = idx & 63;
  int gran = idx >> 6;          // 0 .. 82943
  int qg = gran / 288;          // 288 granules per quad-group (32 kc * 9 t)
  int rem = gran - qg * 288;
  int kc = rem / 9;
  int t = rem - kc * 9;
  int n = lane & 15, q = lane >> 4;
  int k0 = kc * 32 + q * 8;
  int b = qg / 9;
  int g, j;
  if (t < 8) { g = qg * 4 + (t >> 1); j = (t & 1) * 16 + n; }
  else       { g = qg * 4 + (n >> 2); j = 32 + (n & 3); }
  short8 cl8 = *(const short8*)(Lw + (size_t)g * 1024 + k0);
  short8 cr8 = *(const short8*)(Rw + (size_t)(b * 36 + j) * 1024 + k0);
  short8 p;
#pragma unroll
  for (int e = 0; e < 8; ++e)
    p[e] = (short)f2bf(bf2f((unsigned short)cl8[e]) * bf2f((unsigned short)cr8[e]));
  *(short8*)(Pf + (size_t)idx * 8) = p;
}

// ---------------------------------------------------------------------------
// K4: streaming GEMM + max-over-j + residual, 2-chunk-deep DMA pipeline.
// Block: 256 thr (4 waves), one quad-group x 256-d tile; wave = 9 tiles x
// r=4 d-granules (acc 144 AGPR, launch_bounds(256,2) -> 2 blocks/CU).
// grid 2304, bx = dt*288+qg. BK=64 iterations: 4 LDS buffers (2 pairs x 2
// chunks x 9 KB); DMA for iter I+1 issued at top of iter I -> full ~2800 cyc
// window before the end-of-iter vmcnt(0)+barrier drain; one barrier / 2 chunks.
__global__ __launch_bounds__(256, 2) void k_pairwise(
    const unsigned short* __restrict__ Pf, const unsigned short* __restrict__ WS,
    const float* __restrict__ mm, float* __restrict__ out) {
  __shared__ __align__(16) unsigned short lB[4][9 * 512];  // 4 x 9 KB

  const int tid = threadIdx.x;
  const int lane = tid & 63, w = tid >> 6;  // w 0..3
  const int n = lane & 15, q = lane >> 4;
  const int bx = blockIdx.x;
  const int dt = bx / 288, qg = bx % 288;
  const int g0 = qg * 4;

  f32x4 acc[9][4];
#pragma unroll
  for (int t = 0; t < 9; ++t)
#pragma unroll
    for (int r = 0; r < 4; ++r) acc[t][r] = (f32x4){0.f, 0.f, 0.f, 0.f};

  // A granule (dgrp=w*4+r, kc): WS + ((dt*16 + dgrp)*32 + kc)*512 + lane*8
  const unsigned short* Abase = WS + (size_t)(dt * 16 + w * 4) * 32 * 512 + lane * 8;
  // B granule (kc, t): Pf + ((qg*32 + kc)*9 + t)*512 + lane*8
  const unsigned short* Bbase = Pf + (size_t)qg * 32 * 9 * 512;

  // wave w stages tiles {w, 4+w}; wave 0 additionally tile 8.
#define STAGE(kc_, bi_)                                                       \
  do {                                                                        \
    const unsigned short* bn = Bbase + (size_t)((kc_) * 9) * 512 + lane * 8;  \
    gl2lds16(bn + (size_t)w * 512, &lB[bi_][w * 512]);                        \
    gl2lds16(bn + (size_t)(4 + w) * 512, &lB[bi_][(4 + w) * 512]);            \
    if (w == 0) gl2lds16(bn + (size_t)8 * 512, &lB[bi_][8 * 512]);            \
  } while (0)

  short8 aR[4], aN[4];
  // prologue: stage iter 0 (kc=0,1), load A(kc=0)
  STAGE(0, 0);
  STAGE(1, 1);
#pragma unroll
  for (int r = 0; r < 4; ++r)
    aR[r] = *(const short8*)(Abase + (size_t)r * 32 * 512);
  __syncthreads();  // drain -> lB[0],lB[1] ready

  for (int it = 0; it < 16; ++it) {
    const int bp = (it & 1) * 2;
    if (it < 15) {  // stage iter it+1 (chunks 2it+2, 2it+3) into other pair
      STAGE(2 * it + 2, bp ^ 2);
      STAGE(2 * it + 3, (bp ^ 2) + 1);
    }
    // ---- chunk 2it (buffer bp)
#pragma unroll
    for (int r = 0; r < 4; ++r)
      aN[r] = *(const short8*)(Abase + (size_t)(r * 32 + 2 * it + 1) * 512);
    {
      short8 bb[9];
#pragma unroll
      for (int t = 0; t < 9; ++t)
        bb[t] = *(const short8*)(&lB[bp][t * 512 + lane * 8]);
#pragma unroll
      for (int t = 0; t < 9; ++t)
#pragma unroll
        for (int r = 0; r < 4; ++r)
          acc[t][r] = __builtin_amdgcn_mfma_f32_16x16x32_bf16(aR[r], bb[t], acc[t][r], 0, 0, 0);
    }
#pragma unroll
    for (int r = 0; r < 4; ++r) aR[r] = aN[r];
    // ---- chunk 2it+1 (buffer bp+1)
    if (it < 15) {
#pragma unroll
      for (int r = 0; r < 4; ++r)
        aN[r] = *(const short8*)(Abase + (size_t)(r * 32 + 2 * it + 2) * 512);
    }
    {
      short8 bb[9];
#pragma unroll
      for (int t = 0; t < 9; ++t)
        bb[t] = *(const short8*)(&lB[bp + 1][t * 512 + lane * 8]);
#pragma unroll
      for (int t = 0; t < 9; ++t)
#pragma unroll
        for (int r = 0; r < 4; ++r)
          acc[t][r] = __builtin_amdgcn_mfma_f32_16x16x32_bf16(aR[r], bb[t], acc[t][r], 0, 0, 0);
    }
    __syncthreads();  // drains iter it+1's DMA (issued ~2800 cyc earlier)
#pragma unroll
    for (int r = 0; r < 4; ++r) aR[r] = aN[r];
  }
#undef STAGE

  // epilogue: per (r,e,ii): max over full tiles 2ii,2ii+1 (j=n, 16+n) and the
  // shared tile's lanes with n>>2==ii (j=32+(n&3)); xor-reduce over 16 n-lanes.
#pragma unroll
  for (int r = 0; r < 4; ++r) {
#pragma unroll
    for (int e = 0; e < 4; ++e) {
      float vs = acc[8][r][e];
#pragma unroll
      for (int ii = 0; ii < 4; ++ii) {
        float v = fmaxf(acc[ii * 2][r][e], acc[ii * 2 + 1][r][e]);
        v = fmaxf(v, ((n >> 2) == ii) ? vs : -1e30f);
#pragma unroll
        for (int s = 1; s < 16; s <<= 1) v = fmaxf(v, __shfl_xor(v, s, 64));
        if (n == 0) {
          int d = dt * 256 + (w * 4 + r) * 16 + q * 4 + e;
          size_t o = (size_t)(g0 + ii) * 2048 + d;
          out[o] = v + mm[o];
        }
      }
    }
  }
}

// ---------------------------------------------------------------------------
extern "C" void kernel_launch(void* const* d_in, const int* in_sizes, int n_in,
                              void* d_out, int out_size, void* d_ws, size_t ws_size,
                              hipStream_t stream) {
  const float* mm     = (const float*)d_in[0];
  const float* coords = (const float*)d_in[1];
  const float* Wcl    = (const float*)d_in[2];
  const float* Wcr    = (const float*)d_in[3];
  const float* Wcout  = (const float*)d_in[4];
  const float* Wfl    = (const float*)d_in[5];
  const float* Wfr    = (const float*)d_in[6];
  const float* Wfout  = (const float*)d_in[7];
  float* out = (float*)d_out;

  // workspace (bf16 shorts), ~103 MB total
  unsigned short* Lw  = (unsigned short*)d_ws;   // [1152][1024]  cl | fl
  unsigned short* Rw  = Lw + 1152 * 1024;        // [1152][1024]  cr | fr
  unsigned short* WS  = Rw + 1152 * 1024;        // 262144 granules x 8 (Wcat^T frag)
  unsigned short* WS2 = WS + (size_t)262144 * 8; // 262144 granules x 8 ((Wfl|Wfr)^T frag)
  unsigned short* mmb = WS2 + (size_t)262144 * 8;// [1152][2048]  mm in bf16
  unsigned short* Pf  = mmb + (size_t)1152 * 2048; // 82944 granules x 512 (products, 85MB)

  k_prep<<<2304 + 2048, 256, 0, stream>>>(coords, Wcl, Wcr, mm, Wcout, Wfout,
                                          Wfl, Wfr, Lw, Rw, mmb, WS, WS2);
  k_proj_feat<<<dim3(16, 72), 256, 0, stream>>>(mmb, WS2, Lw, Rw);
  k_prod<<<20736, 256, 0, stream>>>(Lw, Rw, Pf);
  k_pairwise<<<2304, 256, 0, stream>>>(Pf, WS, mm, out);
}